// Round 7
// baseline (231.339 us; speedup 1.0000x reference)
//
#include <hip/hip_runtime.h>

#define HSZ 128
#define ISZ 28
#define TSZ 28
#define CSZ 10
#define BT  16     // batch rows per wave
#define NT  64     // ONE wave per block: zero-synchronization design

typedef _Float16 half_t;
typedef _Float16 v8h __attribute__((ext_vector_type(8)));
typedef _Float16 v4h __attribute__((ext_vector_type(4)));
typedef float v4f __attribute__((ext_vector_type(4)));

__device__ __forceinline__ float fast_tanh(float x) {
    // 1 - 2/(e^{2x}+1); saturates correctly (+-inf -> +-1)
    float e = __expf(2.f * x);
    return 1.f - 2.f * __builtin_amdgcn_rcpf(e + 1.f);
}

// MFMA 16x16x32 f16 layouts (HW-verified in rounds 2-4, all passed):
//   A-frag: lane holds A[m = lane&15][k = (lane>>4)*8 + j]
//   B-frag: lane holds B[k = (lane>>4)*8 + j][n = lane&15]
//   C/D   : lane holds D[row = (lane>>4)*4 + r][col = lane&15]
// Frag-linear LDS (verified R2/R4): element (k,n) at half-index
//   (k>>5)*512 + ((k>>3)&3)*128 + n*8 + (k&7)
//   -> B-frag slice ks = one conflict-free ds_read_b128 at ks*512 + lane*8
//   -> D write slot, unit u = rt*16 + quad*4 + r, col ln:
//      (rt>>1)*512 + (rt&1)*256 + (quad>>1)*128 + ln*8 + (quad&1)*4  (v4h)
//
// This kernel has NO __syncthreads and NO flags: every LDS buffer is
// wave-private, and per-wave DS ops execute in program order.
__global__ __launch_bounds__(NT, 1)   // 1 wave/EU -> up to 512 VGPR
void rnn_zsync(const float* __restrict__ x,
               const float* __restrict__ W_ih0, const float* __restrict__ W_hh0,
               const float* __restrict__ b_ih0, const float* __restrict__ b_hh0,
               const float* __restrict__ W_ih1, const float* __restrict__ W_hh1,
               const float* __restrict__ b_ih1, const float* __restrict__ b_hh1,
               const float* __restrict__ fc_w, const float* __restrict__ fc_b,
               float* __restrict__ out)
{
    __shared__ half_t xs[TSZ][512];    // 28 KB: all x, frag-linear, col28 = 1.0
    __shared__ half_t aWxL[8 * 512];   // 8 KB: per-lane stash of W_ih0 A-frags
    __shared__ half_t h0b[2048];       // 4 KB: h0(t) state, frag-linear
    __shared__ half_t h1b[2048];       // 4 KB: h1(t) state, frag-linear

    const int lane = threadIdx.x;      // 0..63
    const int ln   = lane & 15;
    const int quad = lane >> 4;
    const int b0   = blockIdx.x * BT;
    const int ro   = lane * 8;
    const int wbq  = (quad >> 1) * 128 + ln * 8 + (quad & 1) * 4;

    // ---- persistent weights in registers: 96 v8h = 384 VGPR ----
    v8h aW0[8][4], aW1i[8][4], aW1h[8][4];
    v4h bias1h[8];                     // bias1 packed f16: 16 VGPR

#pragma unroll
    for (int rt = 0; rt < 8; ++rt) {
        const int row = rt * 16 + ln;
        {   // W_ih0 A-frag with bias0 folded into k-pad col 28 (R4-verified)
            const float bias = b_ih0[row] + b_hh0[row];
            const float* pw = W_ih0 + row * ISZ + quad * 8;
            float4 a = *(const float4*)pw;
            float4 b = (quad < 3) ? *(const float4*)(pw + 4)
                                  : make_float4(bias, 0.f, 0.f, 0.f);
            v8h f = {(half_t)a.x, (half_t)a.y, (half_t)a.z, (half_t)a.w,
                     (half_t)b.x, (half_t)b.y, (half_t)b.z, (half_t)b.w};
            *(v8h*)&aWxL[rt * 512 + ro] = f;   // per-lane private stash
        }
        {   // bias1 for D rows rt*16 + quad*4 + r (consumer-verified indexing)
            float4 p = *(const float4*)(b_ih1 + rt * 16 + quad * 4);
            float4 q = *(const float4*)(b_hh1 + rt * 16 + quad * 4);
            bias1h[rt] = (v4h){(half_t)(p.x + q.x), (half_t)(p.y + q.y),
                               (half_t)(p.z + q.z), (half_t)(p.w + q.w)};
        }
#pragma unroll
        for (int ks = 0; ks < 4; ++ks) {
            const float4* p0 = (const float4*)(W_hh0 + row * HSZ + ks * 32 + quad * 8);
            const float4* p1 = (const float4*)(W_ih1 + row * HSZ + ks * 32 + quad * 8);
            const float4* p2 = (const float4*)(W_hh1 + row * HSZ + ks * 32 + quad * 8);
            float4 a = p0[0], b = p0[1];
            aW0[rt][ks] = (v8h){(half_t)a.x, (half_t)a.y, (half_t)a.z, (half_t)a.w,
                                (half_t)b.x, (half_t)b.y, (half_t)b.z, (half_t)b.w};
            a = p1[0]; b = p1[1];
            aW1i[rt][ks] = (v8h){(half_t)a.x, (half_t)a.y, (half_t)a.z, (half_t)a.w,
                                 (half_t)b.x, (half_t)b.y, (half_t)b.z, (half_t)b.w};
            a = p2[0]; b = p2[1];
            aW1h[rt][ks] = (v8h){(half_t)a.x, (half_t)a.y, (half_t)a.z, (half_t)a.w,
                                 (half_t)b.x, (half_t)b.y, (half_t)b.z, (half_t)b.w};
        }
    }

    // ---- stage ALL x as f16 frag-linear (R2/R4-verified decode), pad col28=1 ----
    // chunk c: q=c&3 (k-quad), n=(c>>2)&15, t=c>>6;  28*64 = 1792 chunks
#pragma unroll
    for (int it = 0; it < 28; ++it) {
        const int c = lane + it * NT;
        const int q = c & 3;
        const int n = (c >> 2) & 15;
        const int t = c >> 6;
        const float* gp = x + ((size_t)(b0 + n) * TSZ + t) * ISZ + q * 8;
        float4 a = *(const float4*)gp;
        float4 b = (q < 3) ? *(const float4*)(gp + 4) : make_float4(1.f, 0.f, 0.f, 0.f);
        v8h p = {(half_t)a.x, (half_t)a.y, (half_t)a.z, (half_t)a.w,
                 (half_t)b.x, (half_t)b.y, (half_t)b.z, (half_t)b.w};
        *(v8h*)&xs[t][(q * 16 + n) * 8] = p;
    }
    // zero h0(-1), h1(-1)
    {
        const v8h z = {(half_t)0.f, (half_t)0.f, (half_t)0.f, (half_t)0.f,
                       (half_t)0.f, (half_t)0.f, (half_t)0.f, (half_t)0.f};
#pragma unroll
        for (int i = 0; i < 4; ++i) {
            *(v8h*)&h0b[(i * 64 + lane) * 8] = z;
            *(v8h*)&h1b[(i * 64 + lane) * 8] = z;
        }
    }
    // single wave: per-wave DS ordering makes staging visible; no barrier needed

    // ---- main loop: 28 steps, ZERO synchronization ----
    int tof = 0;   // opaque 0: defeats LICM so aWx frags re-read from LDS each
                   // step (keeps peak VGPR < 512 instead of +32 resident)
    for (int t = 0; t < TSZ; ++t) {
        asm volatile("" : "+v"(tof));

        // ---- layer 0: h0(t) = tanh([W_ih0|b0|W_hh0] . [x(t);1;h0(t-1)]) ----
        const v8h bx = *(const v8h*)&xs[t][ro];
        v4f acc[8];
#pragma unroll
        for (int rt = 0; rt < 8; ++rt)
            acc[rt] = __builtin_amdgcn_mfma_f32_16x16x32_f16(
                *(const v8h*)&aWxL[rt * 512 + ro + tof], bx,
                (v4f){0.f, 0.f, 0.f, 0.f}, 0, 0, 0);
#pragma unroll
        for (int ks = 0; ks < 4; ++ks) {
            const v8h bh = *(const v8h*)&h0b[ks * 512 + ro];   // h0(t-1)
#pragma unroll
            for (int rt = 0; rt < 8; ++rt)
                acc[rt] = __builtin_amdgcn_mfma_f32_16x16x32_f16(
                    aW0[rt][ks], bh, acc[rt], 0, 0, 0);
        }
#pragma unroll
        for (int rt = 0; rt < 8; ++rt) {
            v4h p = {(half_t)fast_tanh(acc[rt][0]), (half_t)fast_tanh(acc[rt][1]),
                     (half_t)fast_tanh(acc[rt][2]), (half_t)fast_tanh(acc[rt][3])};
            *(v4h*)&h0b[(rt >> 1) * 512 + (rt & 1) * 256 + wbq] = p;   // h0(t)
        }

        // ---- layer 1: W_hh1 part first (independent of this step's L0) ----
#pragma unroll
        for (int rt = 0; rt < 8; ++rt)
            acc[rt] = (v4f){(float)bias1h[rt][0], (float)bias1h[rt][1],
                            (float)bias1h[rt][2], (float)bias1h[rt][3]};
#pragma unroll
        for (int ks = 0; ks < 4; ++ks) {
            const v8h bh1o = *(const v8h*)&h1b[ks * 512 + ro];  // h1(t-1)
#pragma unroll
            for (int rt = 0; rt < 8; ++rt)
                acc[rt] = __builtin_amdgcn_mfma_f32_16x16x32_f16(
                    aW1h[rt][ks], bh1o, acc[rt], 0, 0, 0);
        }
        // then the W_ih1 part, reading back h0(t) written above (same wave,
        // in-order DS pipe -> no sync needed)
#pragma unroll
        for (int ks = 0; ks < 4; ++ks) {
            const v8h bh0n = *(const v8h*)&h0b[ks * 512 + ro];  // h0(t)
#pragma unroll
            for (int rt = 0; rt < 8; ++rt)
                acc[rt] = __builtin_amdgcn_mfma_f32_16x16x32_f16(
                    aW1i[rt][ks], bh0n, acc[rt], 0, 0, 0);
        }
#pragma unroll
        for (int rt = 0; rt < 8; ++rt) {
            v4h p = {(half_t)fast_tanh(acc[rt][0]), (half_t)fast_tanh(acc[rt][1]),
                     (half_t)fast_tanh(acc[rt][2]), (half_t)fast_tanh(acc[rt][3])};
            *(v4h*)&h1b[(rt >> 1) * 512 + (rt & 1) * 256 + wbq] = p;   // h1(t)
        }
    }

    // ---- FC epilogue: out = h1(27) @ fc_w^T + fc_b (h1(27) is in h1b) ----
    for (int p = lane; p < BT * CSZ; p += NT) {
        const int m = p / CSZ, cc = p - m * CSZ;
        float s = fc_b[cc];
#pragma unroll
        for (int ks = 0; ks < 4; ++ks) {
#pragma unroll
            for (int q2 = 0; q2 < 4; ++q2) {
                const v8h hv = *(const v8h*)&h1b[(ks * 64 + q2 * 16 + m) * 8];
                const int kb = ks * 32 + q2 * 8;
                const float4 w0 = *(const float4*)(fc_w + cc * HSZ + kb);
                const float4 w1 = *(const float4*)(fc_w + cc * HSZ + kb + 4);
                s += (float)hv[0] * w0.x + (float)hv[1] * w0.y +
                     (float)hv[2] * w0.z + (float)hv[3] * w0.w +
                     (float)hv[4] * w1.x + (float)hv[5] * w1.y +
                     (float)hv[6] * w1.z + (float)hv[7] * w1.w;
            }
        }
        out[(b0 + m) * CSZ + cc] = s;
    }
}

extern "C" void kernel_launch(void* const* d_in, const int* in_sizes, int n_in,
                              void* d_out, int out_size, void* d_ws, size_t ws_size,
                              hipStream_t stream) {
    const float* x     = (const float*)d_in[0];
    const float* W_ih0 = (const float*)d_in[1];
    const float* W_hh0 = (const float*)d_in[2];
    const float* b_ih0 = (const float*)d_in[3];
    const float* b_hh0 = (const float*)d_in[4];
    const float* W_ih1 = (const float*)d_in[5];
    const float* W_hh1 = (const float*)d_in[6];
    const float* b_ih1 = (const float*)d_in[7];
    const float* b_hh1 = (const float*)d_in[8];
    const float* fc_w  = (const float*)d_in[9];
    const float* fc_b  = (const float*)d_in[10];
    float* out = (float*)d_out;

    const int B = in_sizes[0] / (TSZ * ISZ);   // 8192
    dim3 grid(B / BT), block(NT);
    rnn_zsync<<<grid, block, 0, stream>>>(x, W_ih0, W_hh0, b_ih0, b_hh0,
                                          W_ih1, W_hh1, b_ih1, b_hh1,
                                          fc_w, fc_b, out);
}

// Round 8
// 126.896 us; speedup vs baseline: 1.8231x; 1.8231x over previous
//
#include <hip/hip_runtime.h>

#define HSZ 128
#define ISZ 28
#define TSZ 28
#define CSZ 10
#define BT  16     // batch rows per block
#define NT  512    // 8 waves, one 16-row hidden tile each
#define HP  136    // h row stride in halves
#define XP  32     // x row stride in halves (K padded 28->32)

typedef _Float16 half_t;
typedef _Float16 v8h __attribute__((ext_vector_type(8)));
typedef _Float16 v4h __attribute__((ext_vector_type(4)));
typedef float v4f __attribute__((ext_vector_type(4)));

__device__ __forceinline__ float fast_tanh(float x) {
    // 1 - 2/(e^{2x}+1); saturates correctly (+-inf -> +-1)
    float e = __expf(2.f * x);
    return 1.f - 2.f * __builtin_amdgcn_rcpf(e + 1.f);
}

// MFMA 16x16x32 f16 layouts (HW-verified):
//   A-frag: lane holds A[m = lane&15][k = (lane>>4)*8 + j], j=0..7
//   B-frag: lane holds B[k = (lane>>4)*8 + j][n = lane&15]
//   C/D   : lane holds D[row = (lane>>4)*4 + r][col = lane&15], r=0..3
// G = W · h^T: A = weight tile (rows = hidden units), B[k][n] = h[batch n][k].
__global__ __launch_bounds__(NT, 4)   // 4 waves/SIMD -> 2 blocks/CU
void rnn_mfma4(const float* __restrict__ x,
               const float* __restrict__ W_ih0, const float* __restrict__ W_hh0,
               const float* __restrict__ b_ih0, const float* __restrict__ b_hh0,
               const float* __restrict__ W_ih1, const float* __restrict__ W_hh1,
               const float* __restrict__ b_ih1, const float* __restrict__ b_hh1,
               const float* __restrict__ fc_w, const float* __restrict__ fc_b,
               float* __restrict__ out)
{
    __shared__ half_t h0s[2][BT * HP];
    __shared__ half_t h1s[2][BT * HP];
    __shared__ half_t xs[TSZ][BT * XP];   // ALL timesteps staged once: 28 KiB

    const int tid  = threadIdx.x;
    const int wave = tid >> 6;          // 0..7 -> row-tile [wave*16, wave*16+16)
    const int lane = tid & 63;
    const int ln   = lane & 15;
    const int quad = lane >> 4;
    const int kq   = quad * 8;
    const int b0   = blockIdx.x * BT;
    const int base = wave * 16;
    const int row  = base + ln;         // A-frag row (hidden unit)

    // ---- persistent weight A-fragments (loaded once): 13 frags ----
    v8h aWx, aW0[4], aW1i[4], aW1h[4];
    v4f bias0, bias1;
    {
        float4 p = *(const float4*)(b_ih0 + base + quad * 4);
        float4 q = *(const float4*)(b_hh0 + base + quad * 4);
        bias0 = (v4f){p.x + q.x, p.y + q.y, p.z + q.z, p.w + q.w};
        p = *(const float4*)(b_ih1 + base + quad * 4);
        q = *(const float4*)(b_hh1 + base + quad * 4);
        bias1 = (v4f){p.x + q.x, p.y + q.y, p.z + q.z, p.w + q.w};
    }
    {
        const float* pw = W_ih0 + row * ISZ + kq;      // kq<=24, kq+3<=27 in-row
        float4 a = *(const float4*)pw;
        float4 b = (kq < 24) ? *(const float4*)(pw + 4) : make_float4(0.f, 0.f, 0.f, 0.f);
        aWx = (v8h){(half_t)a.x, (half_t)a.y, (half_t)a.z, (half_t)a.w,
                    (half_t)b.x, (half_t)b.y, (half_t)b.z, (half_t)b.w};
    }
#pragma unroll
    for (int ks = 0; ks < 4; ++ks) {
        const float4* p0 = (const float4*)(W_hh0 + row * HSZ + ks * 32 + kq);
        const float4* p1 = (const float4*)(W_ih1 + row * HSZ + ks * 32 + kq);
        const float4* p2 = (const float4*)(W_hh1 + row * HSZ + ks * 32 + kq);
        float4 a = p0[0], b = p0[1];
        aW0[ks] = (v8h){(half_t)a.x, (half_t)a.y, (half_t)a.z, (half_t)a.w,
                        (half_t)b.x, (half_t)b.y, (half_t)b.z, (half_t)b.w};
        a = p1[0]; b = p1[1];
        aW1i[ks] = (v8h){(half_t)a.x, (half_t)a.y, (half_t)a.z, (half_t)a.w,
                         (half_t)b.x, (half_t)b.y, (half_t)b.z, (half_t)b.w};
        a = p2[0]; b = p2[1];
        aW1h[ks] = (v8h){(half_t)a.x, (half_t)a.y, (half_t)a.z, (half_t)a.w,
                         (half_t)b.x, (half_t)b.y, (half_t)b.z, (half_t)b.w};
    }

    // ---- stage ALL x for this block's 16 rows as f16, f32->f16, coalesced ----
    // 16 rows x 784 floats = 3136 float4; consecutive tid -> consecutive float4.
    // 784 = 196 float4/row; within a row, float4 F covers t = F/7, i = (F%7)*4
    // (28 % 4 == 0 so a float4 never straddles a timestep).
    {
        const float* xblk = x + (size_t)b0 * (TSZ * ISZ);
#pragma unroll
        for (int k = 0; k < 7; ++k) {
            const int F = tid + k * NT;
            if (F < BT * 196) {
                const int r   = F / 196;
                const int rem = F - r * 196;
                const int t   = rem / 7;
                const int i4  = (rem - t * 7) * 4;
                const float4 v = *(const float4*)(xblk + r * (TSZ * ISZ) + rem * 4);
                v4h p = {(half_t)v.x, (half_t)v.y, (half_t)v.z, (half_t)v.w};
                *(v4h*)&xs[t][r * XP + i4] = p;
            }
        }
        // zero the K-pad (cols 28..31) so 0*garbage can't make NaN in MFMA
        if (tid < TSZ * BT) {
            const int tt = tid >> 4, rr = tid & 15;
            *(v4h*)&xs[tt][rr * XP + ISZ] =
                (v4h){(half_t)0.f, (half_t)0.f, (half_t)0.f, (half_t)0.f};
        }
    }

    for (int idx = tid; idx < BT * HP; idx += NT)
        h1s[0][idx] = (half_t)0.f;              // h1(-1) = 0
    __syncthreads();

    // ---- h0(0) = tanh(W_ih0 x0^T + b0) -> h0s[0] ----
    {
        const v8h bx = *(const v8h*)&xs[0][ln * XP + kq];
        v4f a0 = bias0;
        a0 = __builtin_amdgcn_mfma_f32_16x16x32_f16(aWx, bx, a0, 0, 0, 0);
        v4h p = {(half_t)fast_tanh(a0[0]), (half_t)fast_tanh(a0[1]),
                 (half_t)fast_tanh(a0[2]), (half_t)fast_tanh(a0[3])};
        *(v4h*)&h0s[0][ln * HP + base + quad * 4] = p;
    }
    __syncthreads();

    // ---- main loop: segment t computes h1(t) and h0(t+1) ----
    // unroll 2 -> pr is compile-time in both bodies; all LDS addrs hoisted
#pragma unroll 2
    for (int t = 0; t < TSZ - 1; ++t) {
        const int pr = t & 1;

        // B-fragments from LDS (issue all reads up front)
        v8h bh0[4], bh1[4];
#pragma unroll
        for (int ks = 0; ks < 4; ++ks) {
            bh0[ks] = *(const v8h*)&h0s[pr][ln * HP + ks * 32 + kq];
            bh1[ks] = *(const v8h*)&h1s[pr][ln * HP + ks * 32 + kq];
        }
        const v8h bx = *(const v8h*)&xs[t + 1][ln * XP + kq];

        // three independent accumulator chains (5 / 4 / 4 deep)
        v4f a0  = bias0;
        v4f a1i = bias1;
        v4f a1h = (v4f){0.f, 0.f, 0.f, 0.f};
        a0 = __builtin_amdgcn_mfma_f32_16x16x32_f16(aWx, bx, a0, 0, 0, 0);
#pragma unroll
        for (int ks = 0; ks < 4; ++ks) {
            a1i = __builtin_amdgcn_mfma_f32_16x16x32_f16(aW1i[ks], bh0[ks], a1i, 0, 0, 0);
            a1h = __builtin_amdgcn_mfma_f32_16x16x32_f16(aW1h[ks], bh1[ks], a1h, 0, 0, 0);
            a0  = __builtin_amdgcn_mfma_f32_16x16x32_f16(aW0[ks],  bh0[ks], a0,  0, 0, 0);
        }
        const v4f a1 = a1i + a1h;

        // tanh + packed h writes
        {
            v4h p1 = {(half_t)fast_tanh(a1[0]), (half_t)fast_tanh(a1[1]),
                      (half_t)fast_tanh(a1[2]), (half_t)fast_tanh(a1[3])};
            *(v4h*)&h1s[pr ^ 1][ln * HP + base + quad * 4] = p1;
            v4h p0 = {(half_t)fast_tanh(a0[0]), (half_t)fast_tanh(a0[1]),
                      (half_t)fast_tanh(a0[2]), (half_t)fast_tanh(a0[3])};
            *(v4h*)&h0s[pr ^ 1][ln * HP + base + quad * 4] = p0;
        }

        __syncthreads();
    }

    // ---- final segment: h1(27) only -> h1s[0] ----
    {
        const int pr = (TSZ - 1) & 1;   // = 1
        v4f a1i = bias1;
        v4f a1h = (v4f){0.f, 0.f, 0.f, 0.f};
#pragma unroll
        for (int ks = 0; ks < 4; ++ks) {
            const v8h bh0 = *(const v8h*)&h0s[pr][ln * HP + ks * 32 + kq];
            const v8h bh1 = *(const v8h*)&h1s[pr][ln * HP + ks * 32 + kq];
            a1i = __builtin_amdgcn_mfma_f32_16x16x32_f16(aW1i[ks], bh0, a1i, 0, 0, 0);
            a1h = __builtin_amdgcn_mfma_f32_16x16x32_f16(aW1h[ks], bh1, a1h, 0, 0, 0);
        }
        const v4f a1 = a1i + a1h;
        v4h p1 = {(half_t)fast_tanh(a1[0]), (half_t)fast_tanh(a1[1]),
                  (half_t)fast_tanh(a1[2]), (half_t)fast_tanh(a1[3])};
        *(v4h*)&h1s[pr ^ 1][ln * HP + base + quad * 4] = p1;
    }
    __syncthreads();

    // ---- FC epilogue: out = h1(27) @ fc_w^T + fc_b ----
    if (tid < BT * CSZ) {
        const int m = tid / CSZ, cc = tid - m * CSZ;
        float s = fc_b[cc];
#pragma unroll
        for (int k8 = 0; k8 < HSZ / 8; ++k8) {
            const v8h hv = *(const v8h*)&h1s[0][m * HP + k8 * 8];
            const float4 w0 = *(const float4*)(fc_w + cc * HSZ + k8 * 8);
            const float4 w1 = *(const float4*)(fc_w + cc * HSZ + k8 * 8 + 4);
            s += (float)hv[0] * w0.x + (float)hv[1] * w0.y +
                 (float)hv[2] * w0.z + (float)hv[3] * w0.w +
                 (float)hv[4] * w1.x + (float)hv[5] * w1.y +
                 (float)hv[6] * w1.z + (float)hv[7] * w1.w;
        }
        out[(b0 + m) * CSZ + cc] = s;
    }
}

extern "C" void kernel_launch(void* const* d_in, const int* in_sizes, int n_in,
                              void* d_out, int out_size, void* d_ws, size_t ws_size,
                              hipStream_t stream) {
    const float* x     = (const float*)d_in[0];
    const float* W_ih0 = (const float*)d_in[1];
    const float* W_hh0 = (const float*)d_in[2];
    const float* b_ih0 = (const float*)d_in[3];
    const float* b_hh0 = (const float*)d_in[4];
    const float* W_ih1 = (const float*)d_in[5];
    const float* W_hh1 = (const float*)d_in[6];
    const float* b_ih1 = (const float*)d_in[7];
    const float* b_hh1 = (const float*)d_in[8];
    const float* fc_w  = (const float*)d_in[9];
    const float* fc_b  = (const float*)d_in[10];
    float* out = (float*)d_out;

    const int B = in_sizes[0] / (TSZ * ISZ);   // 8192
    dim3 grid(B / BT), block(NT);
    rnn_mfma4<<<grid, block, 0, stream>>>(x, W_ih0, W_hh0, b_ih0, b_hh0,
                                          W_ih1, W_hh1, b_ih1, b_hh1,
                                          fc_w, fc_b, out);
}